// Round 11
// baseline (255.462 us; speedup 1.0000x reference)
//
#include <hip/hip_runtime.h>

// Dtypes (R1-R6 forensics): floats fp32, edges int32 [E][2], output fp32.
// Workspace intermediates: bf16 (MFMA path).
// Spill law (R6-R9): MFMA accumulators must be NAMED scalars (arrays fail SROA ->
//   scratch) and per-wave reg budget must be >=~demand: use (256,2) = 256 regs/wave.
//   Spill signature: WRITE_SIZE >> output bytes, MfmaUtil ~4%, VGPR_Count < acc count.
// R10: attn pinned ~57us (random-gather path ~46% HBM, 0 conflicts) — near its floor.
// R11: GEMM restructured barrier-free: full-K A-tile persisted in LDS (one barrier),
//   B fragments streamed from L2-resident W, exclusive col-chunks per wave.

typedef __bf16 bf16x8 __attribute__((ext_vector_type(8)));
typedef float  f32x4  __attribute__((ext_vector_type(4)));

__device__ __forceinline__ float bf2f(unsigned short u) {
    union { unsigned int i; float f; } v; v.i = ((unsigned int)u) << 16; return v.f;
}
__device__ __forceinline__ unsigned short f2bf(float f) {
    union { float f; unsigned int i; } v; v.f = f;
    unsigned int x = v.i;
    unsigned int r = (x + 0x7FFFu + ((x >> 16) & 1u)) >> 16;   // RNE
    return (unsigned short)r;
}

#define NNODE 20000
#define ROWS  40000      // B*N
#define DMODEL 256

// ---------- K0: fused prep (blocks 0..1023) + LayerNorm1 (blocks 1024..6023) ----------
__global__ __launch_bounds__(256) void prep_ln1_kernel(
    const float* __restrict__ wq, const float* __restrict__ wk,
    const float* __restrict__ wv, const float* __restrict__ wo,
    const float* __restrict__ bq, const float* __restrict__ bk,
    const float* __restrict__ bv, const float* __restrict__ bo,
    const float* __restrict__ x,
    const float* __restrict__ g1, const float* __restrict__ b1,
    unsigned short* __restrict__ Wqkvt,   // [768][256] bf16
    unsigned short* __restrict__ Wot,     // [256][256] bf16
    float* __restrict__ biasq,            // [768]
    float* __restrict__ biaso,            // [256]
    unsigned short* __restrict__ xn)      // [ROWS][256] bf16
{
    if (blockIdx.x < 1024) {
        int idx = blockIdx.x * 256 + threadIdx.x;
        if (idx < 768 * 256) {
            int n = idx >> 8, k = idx & 255;
            int sel = n >> 8, nl = n & 255;
            const float* w = (sel == 0) ? wq : (sel == 1) ? wk : wv;
            Wqkvt[idx] = f2bf(w[k * 256 + nl]);
        } else {
            int idx2 = idx - 768 * 256;        // [0, 65536)
            int n = idx2 >> 8, k = idx2 & 255;
            Wot[idx2] = f2bf(wo[k * 256 + n]);
        }
        if (idx < 768) {
            const float* bb = (idx < 256) ? bq : (idx < 512) ? bk : bv;
            biasq[idx] = bb[idx & 255];
        }
        if (idx >= 768 && idx < 1024) biaso[idx - 768] = bo[idx - 768];
        return;
    }
    // ---- LN1: half-wave (32 lanes) per row, 8 elems/lane ----
    int wave = threadIdx.x >> 6, lane = threadIdx.x & 63;
    int sub = lane >> 5, hl = lane & 31;
    int m = (blockIdx.x - 1024) * 8 + wave * 2 + sub;
    const float* xp = x + (size_t)m * DMODEL + hl * 8;
    float4 x0 = *(const float4*)xp;
    float4 x1 = *(const float4*)(xp + 4);
    float f[8] = {x0.x, x0.y, x0.z, x0.w, x1.x, x1.y, x1.z, x1.w};
    float s = 0.f, ss = 0.f;
    #pragma unroll
    for (int t = 0; t < 8; ++t) { s += f[t]; ss += f[t]*f[t]; }
    #pragma unroll
    for (int mk = 1; mk < 32; mk <<= 1) { s += __shfl_xor(s, mk); ss += __shfl_xor(ss, mk); }
    float mu  = s * (1.f/256.f);
    float var = ss * (1.f/256.f) - mu*mu;
    float rs  = rsqrtf(var + 1e-3f);
    float4 g0 = *(const float4*)(g1 + hl * 8);
    float4 g1v = *(const float4*)(g1 + hl * 8 + 4);
    float4 b0 = *(const float4*)(b1 + hl * 8);
    float4 b1v = *(const float4*)(b1 + hl * 8 + 4);
    float gg[8] = {g0.x, g0.y, g0.z, g0.w, g1v.x, g1v.y, g1v.z, g1v.w};
    float bb[8] = {b0.x, b0.y, b0.z, b0.w, b1v.x, b1v.y, b1v.z, b1v.w};
    unsigned short o[8];
    #pragma unroll
    for (int t = 0; t < 8; ++t) o[t] = f2bf((f[t] - mu) * rs * gg[t] + bb[t]);
    *(int4*)(xn + (size_t)m * DMODEL + hl * 8) = *(const int4*)o;
}

// ---------- K2/K4: barrier-free bf16 MFMA GEMM ----------
// Block = 64 rows, full Ncols. A-tile (64 x 256, full K) persisted in LDS; ONE barrier.
// B fragments streamed straight from global (W is L2-resident, 0.4 MB).
// Wave w owns exclusive 32-col chunks: col0 = w*32 + s*128, s in [0, NCHUNK).
// Per chunk: 8 named f32x4 accs (4 row-frags x 2 col-frags), K-loop 8 x 32.
#define AS_W 264   // LDS row stride in shorts (16B-aligned rows; same bank class as R8's 72)
#define MFMA_BF16(d, a, b) d = __builtin_amdgcn_mfma_f32_16x16x32_bf16(a, b, d, 0, 0, 0)

template<bool EPI, int NCHUNK>
__global__ __launch_bounds__(256, 2) void gemm2_kernel(
    const unsigned short* __restrict__ A,     // [M][256] bf16
    const unsigned short* __restrict__ Bt,    // [Ncols][256] bf16
    const float* __restrict__ bias,
    void* __restrict__ C,
    const unsigned short* __restrict__ resid, // [M][256] bf16 (EPI only)
    int Ncols)
{
    __shared__ unsigned short As[64 * AS_W];  // 33 KB
    int tid  = threadIdx.x;
    int wave = tid >> 6, lane = tid & 63;
    int quad = lane >> 4, l16 = lane & 15;
    int m0 = blockIdx.x * 64;                 // 625 * 64 = 40000 exact, no tail

    // ---- stage A once: thread t -> row t>>2, shorts [(t&3)*64, +64) (8 x int4) ----
    {
        int r = tid >> 2, c = (tid & 3) * 64;
        const unsigned short* src = A + (size_t)(m0 + r) * 256 + c;
        unsigned short* dst = &As[r * AS_W + c];
        int4 t0 = *(const int4*)(src);
        int4 t1 = *(const int4*)(src + 8);
        int4 t2 = *(const int4*)(src + 16);
        int4 t3 = *(const int4*)(src + 24);
        int4 t4 = *(const int4*)(src + 32);
        int4 t5 = *(const int4*)(src + 40);
        int4 t6 = *(const int4*)(src + 48);
        int4 t7 = *(const int4*)(src + 56);
        *(int4*)(dst)      = t0;
        *(int4*)(dst + 8)  = t1;
        *(int4*)(dst + 16) = t2;
        *(int4*)(dst + 24) = t3;
        *(int4*)(dst + 32) = t4;
        *(int4*)(dst + 40) = t5;
        *(int4*)(dst + 48) = t6;
        *(int4*)(dst + 56) = t7;
    }
    __syncthreads();                          // the ONLY barrier

    #pragma unroll
    for (int s = 0; s < NCHUNK; ++s) {
        int col0 = wave * 32 + s * 128;
        const unsigned short* Bp = Bt + (size_t)(col0 + l16) * 256 + quad * 8;

        f32x4 c0a = {}, c0b = {}, c1a = {}, c1b = {};
        f32x4 c2a = {}, c2b = {}, c3a = {}, c3b = {};

        #pragma unroll
        for (int kt = 0; kt < 8; ++kt) {
            bf16x8 a0 = *(const bf16x8*)&As[( 0 + l16) * AS_W + kt * 32 + quad * 8];
            bf16x8 a1 = *(const bf16x8*)&As[(16 + l16) * AS_W + kt * 32 + quad * 8];
            bf16x8 a2 = *(const bf16x8*)&As[(32 + l16) * AS_W + kt * 32 + quad * 8];
            bf16x8 a3 = *(const bf16x8*)&As[(48 + l16) * AS_W + kt * 32 + quad * 8];
            bf16x8 b0 = *(const bf16x8*)(Bp + kt * 32);              // col frag 0
            bf16x8 b1 = *(const bf16x8*)(Bp + 16 * 256 + kt * 32);   // col frag 1 (+16 cols)
            MFMA_BF16(c0a, a0, b0); MFMA_BF16(c0b, a0, b1);
            MFMA_BF16(c1a, a1, b0); MFMA_BF16(c1b, a1, b1);
            MFMA_BF16(c2a, a2, b0); MFMA_BF16(c2b, a2, b1);
            MFMA_BF16(c3a, a3, b0); MFMA_BF16(c3b, a3, b1);
        }

#define EPI_ST(accv, RF, CF) do {                                            \
        int col = col0 + (CF) * 16 + l16;                                    \
        float bb = bias[col];                                                \
        int rowb = m0 + (RF) * 16 + quad * 4;                                \
        _Pragma("unroll")                                                    \
        for (int rr = 0; rr < 4; ++rr) {                                     \
            int row = rowb + rr;                                             \
            float v = (accv)[rr] + bb;                                       \
            if (EPI) {                                                       \
                v = fmaxf(v, 0.f);                                           \
                v += bf2f(resid[(size_t)row * 256 + col]);                   \
                ((float*)C)[(size_t)row * Ncols + col] = v;                  \
            } else {                                                         \
                ((unsigned short*)C)[(size_t)row * Ncols + col] = f2bf(v);   \
            }                                                                \
        }                                                                    \
    } while (0)

        EPI_ST(c0a, 0, 0); EPI_ST(c0b, 0, 1);
        EPI_ST(c1a, 1, 0); EPI_ST(c1b, 1, 1);
        EPI_ST(c2a, 2, 0); EPI_ST(c2b, 2, 1);
        EPI_ST(c3a, 3, 0); EPI_ST(c3b, 3, 1);
#undef EPI_ST
    }
}

// ---------- K3: edge attention + residual + LN2 — wave = node, half-wave = batch ----------
__global__ __launch_bounds__(256) void attn_kernel(
    const unsigned short* __restrict__ qkv,   // [ROWS][768] bf16: q|k|v
    const int* __restrict__ edges,            // int32 [E][2]
    const unsigned short* __restrict__ xn,    // [ROWS][256] bf16
    const float* __restrict__ g2, const float* __restrict__ b2,
    unsigned short* __restrict__ concat,      // [ROWS][256] bf16
    unsigned short* __restrict__ h2)          // [ROWS][256] bf16
{
    int wave = threadIdx.x >> 6, lane = threadIdx.x & 63;
    int i = blockIdx.x * 4 + wave;            // node id
    int b = lane >> 5, hl = lane & 31;        // batch half, 8 dims/lane
    size_t m = (size_t)b * NNODE + i;

    int4 qi = *(const int4*)(qkv + m * 768 + hl * 8);
    const unsigned short* qs = (const unsigned short*)&qi;
    float qf[8];
    #pragma unroll
    for (int t = 0; t < 8; ++t) qf[t] = bf2f(qs[t]);

    int jv = 0;
    if (lane < 8) jv = edges[2 * (i * 8 + lane) + 1];   // int32 dst of edge

#define KVLOAD(E)                                                                  \
    int j##E = __shfl(jv, E);                                                      \
    const unsigned short* kp##E = qkv + ((size_t)b * NNODE + j##E) * 768 + 256 + hl * 8; \
    int4 KI##E = *(const int4*)(kp##E);                                            \
    int4 VI##E = *(const int4*)(kp##E + 256);
    KVLOAD(0) KVLOAD(1) KVLOAD(2) KVLOAD(3)
    KVLOAD(4) KVLOAD(5) KVLOAD(6) KVLOAD(7)
#undef KVLOAD

    float acc[8] = {};
    float den = 0.f;
    const float scale = 0.17677669529663687f;           // 1/sqrt(32)
#define EDGE(E) do {                                                         \
        const unsigned short* ks = (const unsigned short*)&KI##E;            \
        const unsigned short* vs = (const unsigned short*)&VI##E;            \
        float dot = 0.f;                                                     \
        _Pragma("unroll")                                                    \
        for (int t = 0; t < 8; ++t) dot += qf[t] * bf2f(ks[t]);              \
        dot += __shfl_xor(dot, 1);                                           \
        dot += __shfl_xor(dot, 2);            /* head = 4 lanes (dh=32) */   \
        float w = __expf(dot * scale);                                       \
        _Pragma("unroll")                                                    \
        for (int t = 0; t < 8; ++t) acc[t] += w * bf2f(vs[t]);               \
        den += w;                                                            \
    } while (0)
    EDGE(0); EDGE(1); EDGE(2); EDGE(3);
    EDGE(4); EDGE(5); EDGE(6); EDGE(7);
#undef EDGE
    float inv = 1.f / den;

    int4 xi = *(const int4*)(xn + m * DMODEL + hl * 8);
    const unsigned short* xs = (const unsigned short*)&xi;
    float c[8], s = 0.f, ss = 0.f;
    #pragma unroll
    for (int t = 0; t < 8; ++t) { c[t] = bf2f(xs[t]) + acc[t] * inv; s += c[t]; ss += c[t]*c[t]; }
    #pragma unroll
    for (int mk = 1; mk < 32; mk <<= 1) { s += __shfl_xor(s, mk); ss += __shfl_xor(ss, mk); }
    float mu  = s * (1.f/256.f);
    float var = ss * (1.f/256.f) - mu*mu;
    float rs  = rsqrtf(var + 1e-3f);

    float4 ga = *(const float4*)(g2 + hl * 8);
    float4 gb = *(const float4*)(g2 + hl * 8 + 4);
    float4 ba = *(const float4*)(b2 + hl * 8);
    float4 bb = *(const float4*)(b2 + hl * 8 + 4);
    float gg[8] = {ga.x, ga.y, ga.z, ga.w, gb.x, gb.y, gb.z, gb.w};
    float bv[8] = {ba.x, ba.y, ba.z, ba.w, bb.x, bb.y, bb.z, bb.w};
    unsigned short oc[8], oh[8];
    #pragma unroll
    for (int t = 0; t < 8; ++t) {
        oc[t] = f2bf(c[t]);
        oh[t] = f2bf((c[t] - mu) * rs * gg[t] + bv[t]);
    }
    *(int4*)(concat + m * DMODEL + hl * 8) = *(const int4*)oc;
    *(int4*)(h2     + m * DMODEL + hl * 8) = *(const int4*)oh;
}

// ---------- launch ----------
extern "C" void kernel_launch(void* const* d_in, const int* in_sizes, int n_in,
                              void* d_out, int out_size, void* d_ws, size_t ws_size,
                              hipStream_t stream)
{
    const float* x   = (const float*)d_in[0];
    const int* edges = (const int*)d_in[1];
    const float* wq = (const float*)d_in[2];
    const float* bq = (const float*)d_in[3];
    const float* wk = (const float*)d_in[4];
    const float* bk = (const float*)d_in[5];
    const float* wv = (const float*)d_in[6];
    const float* bv = (const float*)d_in[7];
    const float* wo = (const float*)d_in[8];
    const float* bo = (const float*)d_in[9];
    const float* g1 = (const float*)d_in[10];
    const float* b1 = (const float*)d_in[11];
    const float* g2 = (const float*)d_in[12];
    const float* b2 = (const float*)d_in[13];

    char* ws = (char*)d_ws;
    unsigned short* Wqkvt = (unsigned short*)(ws);                    // 393216 B
    unsigned short* Wot   = (unsigned short*)(ws + 393216);           // 131072 B
    float* biasq          = (float*)(ws + 393216 + 131072);           // 3072 B
    float* biaso          = (float*)(ws + 393216 + 131072 + 3072);    // 1024 B
    size_t off = 393216 + 131072 + 4096;
    unsigned short* xn     = (unsigned short*)(ws + off); off += (size_t)ROWS * DMODEL * 2;
    unsigned short* qkv    = (unsigned short*)(ws + off); off += (size_t)ROWS * 768 * 2;
    unsigned short* concat = (unsigned short*)(ws + off); off += (size_t)ROWS * DMODEL * 2;
    unsigned short* h2     = (unsigned short*)(ws + off); off += (size_t)ROWS * DMODEL * 2;

    prep_ln1_kernel<<<1024 + ROWS / 8, 256, 0, stream>>>(
        wq, wk, wv, wo, bq, bk, bv, bo, x, g1, b1, Wqkvt, Wot, biasq, biaso, xn);
    gemm2_kernel<false, 6><<<625, 256, 0, stream>>>(xn, Wqkvt, biasq, qkv, nullptr, 768);
    attn_kernel<<<NNODE / 4, 256, 0, stream>>>(qkv, edges, xn, g2, b2, concat, h2);
    gemm2_kernel<true, 2><<<625, 256, 0, stream>>>(h2, Wot, biaso, d_out, concat, 256);
}